// Round 1
// baseline (7359.816 us; speedup 1.0000x reference)
//
#include <hip/hip_runtime.h>
#include <hip/hip_bf16.h>
#include <math.h>

// Problem constants (match reference)
#define NN 50000      // nodes
#define NE 800000     // edges
#define DD 256        // feature dim
#define NSTEPS 6

// GEMM tiling
#define TM 64
#define TN 64
#define TK 32

__device__ __forceinline__ float sigmoidf_(float v) {
    return 1.0f / (1.0f + expf(-v));
}

// ---------------- CSR build ----------------

__global__ void zero_kernel(int* __restrict__ p, int n) {
    int i = blockIdx.x * blockDim.x + threadIdx.x;
    if (i < n) p[i] = 0;
}

__global__ void hist_kernel(const int* __restrict__ dst, int* __restrict__ counts, int E) {
    int e = blockIdx.x * blockDim.x + threadIdx.x;
    if (e < E) atomicAdd(&counts[dst[e]], 1);
}

// single-block exclusive scan of counts[0..n) -> row_ptr[0..n], row_ptr[n]=total
__global__ void scan_kernel(const int* __restrict__ counts, int* __restrict__ row_ptr, int n) {
    __shared__ int buf[1024];
    __shared__ int carry;
    const int tid = threadIdx.x;
    if (tid == 0) carry = 0;
    __syncthreads();
    for (int base = 0; base < n; base += 1024) {
        int i = base + tid;
        int v = (i < n) ? counts[i] : 0;
        buf[tid] = v;
        __syncthreads();
        for (int off = 1; off < 1024; off <<= 1) {
            int t = (tid >= off) ? buf[tid - off] : 0;
            __syncthreads();
            buf[tid] += t;
            __syncthreads();
        }
        if (i < n) row_ptr[i] = carry + buf[tid] - v;   // exclusive
        __syncthreads();
        if (tid == 0) carry += buf[1023];
        __syncthreads();
    }
    if (threadIdx.x == 0) row_ptr[n] = carry;
}

__global__ void fill_kernel(const int* __restrict__ src, const int* __restrict__ dst,
                            const int* __restrict__ row_ptr, int* __restrict__ cursor,
                            int* __restrict__ csr_src, int E) {
    int e = blockIdx.x * blockDim.x + threadIdx.x;
    if (e < E) {
        int d = dst[e];
        int p = atomicAdd(&cursor[d], 1);
        csr_src[row_ptr[d] + p] = src[e];
    }
}

// ---------------- GEMM: C = act(A @ W^T + bias) ----------------
// A: [M,K] row-major, W: [N,K] row-major (torch Linear weight), C: [M,N]
template <bool RELU>
__global__ __launch_bounds__(256)
void gemm_nt(const float* __restrict__ A, const float* __restrict__ W,
             const float* __restrict__ bias, float* __restrict__ C,
             int M, int Nn, int K) {
    __shared__ float As[TK][TM + 4];
    __shared__ float Ws[TK][TN + 4];
    const int tid = threadIdx.x;
    const int tx = tid & 15;
    const int ty = tid >> 4;
    const int rowBase = blockIdx.x * TM;
    const int colBase = blockIdx.y * TN;

    float acc[4][4] = {};

    for (int k0 = 0; k0 < K; k0 += TK) {
#pragma unroll
        for (int rep = 0; rep < 2; ++rep) {
            int idx = tid + rep * 256;     // 0..511  (64 rows x 8 float4)
            int r   = idx >> 3;            // 0..63
            int c4  = (idx & 7) * 4;       // 0..28
            int gr  = rowBase + r;
            float4 v = make_float4(0.f, 0.f, 0.f, 0.f);
            if (gr < M) v = *reinterpret_cast<const float4*>(&A[(size_t)gr * K + k0 + c4]);
            As[c4 + 0][r] = v.x; As[c4 + 1][r] = v.y; As[c4 + 2][r] = v.z; As[c4 + 3][r] = v.w;
            int gw = colBase + r;          // output column = W row (always < Nn here)
            float4 w = *reinterpret_cast<const float4*>(&W[(size_t)gw * K + k0 + c4]);
            Ws[c4 + 0][r] = w.x; Ws[c4 + 1][r] = w.y; Ws[c4 + 2][r] = w.z; Ws[c4 + 3][r] = w.w;
        }
        __syncthreads();
#pragma unroll
        for (int kk = 0; kk < TK; ++kk) {
            float4 a = *reinterpret_cast<const float4*>(&As[kk][ty * 4]);
            float4 b = *reinterpret_cast<const float4*>(&Ws[kk][tx * 4]);
            float av[4] = {a.x, a.y, a.z, a.w};
            float bv[4] = {b.x, b.y, b.z, b.w};
#pragma unroll
            for (int i = 0; i < 4; ++i)
#pragma unroll
                for (int j = 0; j < 4; ++j)
                    acc[i][j] = fmaf(av[i], bv[j], acc[i][j]);
        }
        __syncthreads();
    }

    const int gc0 = colBase + tx * 4;
    float4 bb = *reinterpret_cast<const float4*>(&bias[gc0]);
    float biasv[4] = {bb.x, bb.y, bb.z, bb.w};
#pragma unroll
    for (int i = 0; i < 4; ++i) {
        int gr = rowBase + ty * 4 + i;
        if (gr >= M) continue;
        float4 o;
        float* ov = reinterpret_cast<float*>(&o);
#pragma unroll
        for (int j = 0; j < 4; ++j) {
            float v = acc[i][j] + biasv[j];
            if (RELU) v = fmaxf(v, 0.0f);
            ov[j] = v;
        }
        *reinterpret_cast<float4*>(&C[(size_t)gr * Nn + gc0]) = o;
    }
}

// ---------------- segment sum (gather over CSR) ----------------
// block: (64, 4) — one wave per node, float4 per lane
__global__ __launch_bounds__(256)
void segsum_kernel(const float* __restrict__ h, const int* __restrict__ row_ptr,
                   const int* __restrict__ csr_src, float* __restrict__ msg, int n) {
    int node = blockIdx.x * 4 + threadIdx.y;
    if (node >= n) return;
    int d4 = threadIdx.x * 4;
    int s = row_ptr[node];
    int e = row_ptr[node + 1];
    float4 acc = make_float4(0.f, 0.f, 0.f, 0.f);
    for (int j = s; j < e; ++j) {
        int sn = csr_src[j];
        float4 v = *reinterpret_cast<const float4*>(&h[(size_t)sn * DD + d4]);
        acc.x += v.x; acc.y += v.y; acc.z += v.z; acc.w += v.w;
    }
    *reinterpret_cast<float4*>(&msg[(size_t)node * DD + d4]) = acc;
}

// ---------------- fused GRU ----------------
// out = (1-z)*n + z*x   with r,z,n per torch GRUCell (input=msg, hidden=x)
// Per output (m,d):
//   acc_r  = sum_k msg*Wih[d]    + x*Whh[d]
//   acc_z  = sum_k msg*Wih[D+d]  + x*Whh[D+d]
//   acc_n1 = sum_k msg*Wih[2D+d]
//   acc_n2 = sum_k x  *Whh[2D+d]
__global__ __launch_bounds__(256)
void gru_kernel(const float* __restrict__ msg, const float* __restrict__ x,
                const float* __restrict__ Wih, const float* __restrict__ Whh,
                const float* __restrict__ bih, const float* __restrict__ bhh,
                float* __restrict__ out, int M) {
    __shared__ float Am[TK][TM + 4];
    __shared__ float Ax[TK][TM + 4];
    __shared__ float Wt[6][TK][TN + 4];   // 0..2: Wih rows {d, D+d, 2D+d}; 3..5: Whh same

    const int tid = threadIdx.x;
    const int tx = tid & 15;
    const int ty = tid >> 4;
    const int rowBase = blockIdx.x * TM;
    const int colBase = blockIdx.y * TN;

    float accr[4][4] = {};
    float accz[4][4] = {};
    float accn1[4][4] = {};
    float accn2[4][4] = {};

    for (int k0 = 0; k0 < DD; k0 += TK) {
#pragma unroll
        for (int rep = 0; rep < 2; ++rep) {
            int idx = tid + rep * 256;
            int r   = idx >> 3;
            int c4  = (idx & 7) * 4;
            int gr  = rowBase + r;
            float4 vm = make_float4(0.f, 0.f, 0.f, 0.f);
            float4 vx = vm;
            if (gr < M) {
                vm = *reinterpret_cast<const float4*>(&msg[(size_t)gr * DD + k0 + c4]);
                vx = *reinterpret_cast<const float4*>(&x[(size_t)gr * DD + k0 + c4]);
            }
            Am[c4 + 0][r] = vm.x; Am[c4 + 1][r] = vm.y; Am[c4 + 2][r] = vm.z; Am[c4 + 3][r] = vm.w;
            Ax[c4 + 0][r] = vx.x; Ax[c4 + 1][r] = vx.y; Ax[c4 + 2][r] = vx.z; Ax[c4 + 3][r] = vx.w;
#pragma unroll
            for (int ws = 0; ws < 6; ++ws) {
                const float* Wp = (ws < 3) ? Wih : Whh;
                int wrow = (ws % 3) * DD + colBase + r;
                float4 wv = *reinterpret_cast<const float4*>(&Wp[(size_t)wrow * DD + k0 + c4]);
                Wt[ws][c4 + 0][r] = wv.x; Wt[ws][c4 + 1][r] = wv.y;
                Wt[ws][c4 + 2][r] = wv.z; Wt[ws][c4 + 3][r] = wv.w;
            }
        }
        __syncthreads();
#pragma unroll
        for (int kk = 0; kk < TK; ++kk) {
            float4 am4 = *reinterpret_cast<const float4*>(&Am[kk][ty * 4]);
            float4 ax4 = *reinterpret_cast<const float4*>(&Ax[kk][ty * 4]);
            float4 w0 = *reinterpret_cast<const float4*>(&Wt[0][kk][tx * 4]);
            float4 w1 = *reinterpret_cast<const float4*>(&Wt[1][kk][tx * 4]);
            float4 w2 = *reinterpret_cast<const float4*>(&Wt[2][kk][tx * 4]);
            float4 w3 = *reinterpret_cast<const float4*>(&Wt[3][kk][tx * 4]);
            float4 w4 = *reinterpret_cast<const float4*>(&Wt[4][kk][tx * 4]);
            float4 w5 = *reinterpret_cast<const float4*>(&Wt[5][kk][tx * 4]);
            float am[4] = {am4.x, am4.y, am4.z, am4.w};
            float ax[4] = {ax4.x, ax4.y, ax4.z, ax4.w};
            float w0v[4] = {w0.x, w0.y, w0.z, w0.w};
            float w1v[4] = {w1.x, w1.y, w1.z, w1.w};
            float w2v[4] = {w2.x, w2.y, w2.z, w2.w};
            float w3v[4] = {w3.x, w3.y, w3.z, w3.w};
            float w4v[4] = {w4.x, w4.y, w4.z, w4.w};
            float w5v[4] = {w5.x, w5.y, w5.z, w5.w};
#pragma unroll
            for (int i = 0; i < 4; ++i) {
#pragma unroll
                for (int j = 0; j < 4; ++j) {
                    accr[i][j]  = fmaf(am[i], w0v[j], accr[i][j]);
                    accr[i][j]  = fmaf(ax[i], w3v[j], accr[i][j]);
                    accz[i][j]  = fmaf(am[i], w1v[j], accz[i][j]);
                    accz[i][j]  = fmaf(ax[i], w4v[j], accz[i][j]);
                    accn1[i][j] = fmaf(am[i], w2v[j], accn1[i][j]);
                    accn2[i][j] = fmaf(ax[i], w5v[j], accn2[i][j]);
                }
            }
        }
        __syncthreads();
    }

    const int gd0 = colBase + tx * 4;
#pragma unroll
    for (int i = 0; i < 4; ++i) {
        int gr = rowBase + ty * 4 + i;
        if (gr >= M) continue;
        float4 o;
        float* ov = reinterpret_cast<float*>(&o);
#pragma unroll
        for (int j = 0; j < 4; ++j) {
            int gd = gd0 + j;
            float r = sigmoidf_(accr[i][j] + bih[gd] + bhh[gd]);
            float z = sigmoidf_(accz[i][j] + bih[DD + gd] + bhh[DD + gd]);
            float nn = tanhf(accn1[i][j] + bih[2 * DD + gd] +
                             r * (accn2[i][j] + bhh[2 * DD + gd]));
            float hp = x[(size_t)gr * DD + gd];
            ov[j] = (1.0f - z) * nn + z * hp;
        }
        *reinterpret_cast<float4*>(&out[(size_t)gr * DD + gd0]) = o;
    }
}

// ---------------- launch ----------------

extern "C" void kernel_launch(void* const* d_in, const int* in_sizes, int n_in,
                              void* d_out, int out_size, void* d_ws, size_t ws_size,
                              hipStream_t stream) {
    const float* x0  = (const float*)d_in[0];
    const float* W1  = (const float*)d_in[1];
    const float* b1  = (const float*)d_in[2];
    const float* W2  = (const float*)d_in[3];
    const float* b2  = (const float*)d_in[4];
    const float* Wih = (const float*)d_in[5];
    const float* bih = (const float*)d_in[6];
    const float* Whh = (const float*)d_in[7];
    const float* bhh = (const float*)d_in[8];
    const int*   src = (const int*)d_in[9];
    const int*   dst = (const int*)d_in[10];

    // workspace layout (~208.5 MB total)
    char* ws = (char*)d_ws;
    const size_t NB = (size_t)NN * DD * sizeof(float);   // 51.2 MB
    float* xa   = (float*)(ws);
    float* xb   = (float*)(ws + NB);
    float* bufA = (float*)(ws + 2 * NB);   // t1, then msg
    float* bufB = (float*)(ws + 3 * NB);   // h
    int* counts  = (int*)(ws + 4 * NB);
    int* cursor  = counts + NN;
    int* row_ptr = cursor + NN;            // NN+1 ints
    int* csr     = row_ptr + NN + 8;       // NE ints

    // ---- CSR build (per launch; deterministic work) ----
    zero_kernel<<<(2 * NN + 255) / 256, 256, 0, stream>>>(counts, 2 * NN);
    hist_kernel<<<(NE + 255) / 256, 256, 0, stream>>>(dst, counts, NE);
    scan_kernel<<<1, 1024, 0, stream>>>(counts, row_ptr, NN);
    fill_kernel<<<(NE + 255) / 256, 256, 0, stream>>>(src, dst, row_ptr, cursor, csr, NE);

    const dim3 gemmGrid((NN + TM - 1) / TM, DD / TN);    // 782 x 4

    for (int s = 0; s < NSTEPS; ++s) {
        const float* x = (s == 0) ? x0 : ((s & 1) ? xb : xa);
        float* xnext   = (s == NSTEPS - 1) ? (float*)d_out : ((s & 1) ? xa : xb);

        // t1 = ReLU(x @ W1^T + b1)
        gemm_nt<true><<<gemmGrid, 256, 0, stream>>>(x, W1, b1, bufA, NN, DD, DD);
        // h = t1 @ W2^T + b2
        gemm_nt<false><<<gemmGrid, 256, 0, stream>>>(bufA, W2, b2, bufB, NN, DD, DD);
        // msg = segment_sum(h[src], dst)   (bufA is dead, reuse for msg)
        segsum_kernel<<<dim3((NN + 3) / 4), dim3(64, 4), 0, stream>>>(bufB, row_ptr, csr, bufA, NN);
        // GRU update -> xnext
        gru_kernel<<<gemmGrid, 256, 0, stream>>>(bufA, x, Wih, Whh, bih, bhh, xnext, NN);
    }
}

// Round 2
// 4244.902 us; speedup vs baseline: 1.7338x; 1.7338x over previous
//
#include <hip/hip_runtime.h>
#include <hip/hip_bf16.h>
#include <math.h>

// Problem constants
#define NN 50000
#define NNP 50048       // rows padded to multiple of 128 (BM)
#define NE 800000
#define DD 256
#define NSTEPS 6

// GEMM tiling
#define BM 128
#define BN 64
#define BK 32
#define LDP 40          // LDS row pitch (bf16 elems): 80B, multiple of 16B

typedef unsigned short u16;
typedef short bf16x8 __attribute__((ext_vector_type(8)));
typedef float f32x4 __attribute__((ext_vector_type(4)));

#define M_PLAIN 0
#define M_RELU  1
#define M_RGATE 2
#define M_ZGATE 3

__device__ __forceinline__ float sigmoidf_(float v) {
    return 1.0f / (1.0f + expf(-v));
}

__device__ __forceinline__ u16 f2bf(float v) {
    union { float f; unsigned u; } x; x.f = v;
    unsigned r = x.u + 0x7FFFu + ((x.u >> 16) & 1u);   // RNE
    return (u16)(r >> 16);
}
__device__ __forceinline__ float bf2f(u16 b) {
    union { unsigned u; float f; } x; x.u = ((unsigned)b) << 16;
    return x.f;
}
// exact 3-way split: v == hi + mid + lo (24 significand bits captured)
__device__ __forceinline__ void split3(float v, u16& h, u16& m, u16& l) {
    h = f2bf(v);
    float r1 = v - bf2f(h);
    m = f2bf(r1);
    float r2 = r1 - bf2f(m);
    l = f2bf(r2);
}
__device__ __forceinline__ unsigned pk(u16 a, u16 b) {
    return (unsigned)a | ((unsigned)b << 16);
}

// ---------------- CSR build (unchanged from R1, verified) ----------------

__global__ void zero_kernel(int* __restrict__ p, int n) {
    int i = blockIdx.x * blockDim.x + threadIdx.x;
    if (i < n) p[i] = 0;
}

__global__ void hist_kernel(const int* __restrict__ dst, int* __restrict__ counts, int E) {
    int e = blockIdx.x * blockDim.x + threadIdx.x;
    if (e < E) atomicAdd(&counts[dst[e]], 1);
}

__global__ void scan_kernel(const int* __restrict__ counts, int* __restrict__ row_ptr, int n) {
    __shared__ int buf[1024];
    __shared__ int carry;
    const int tid = threadIdx.x;
    if (tid == 0) carry = 0;
    __syncthreads();
    for (int base = 0; base < n; base += 1024) {
        int i = base + tid;
        int v = (i < n) ? counts[i] : 0;
        buf[tid] = v;
        __syncthreads();
        for (int off = 1; off < 1024; off <<= 1) {
            int t = (tid >= off) ? buf[tid - off] : 0;
            __syncthreads();
            buf[tid] += t;
            __syncthreads();
        }
        if (i < n) row_ptr[i] = carry + buf[tid] - v;
        __syncthreads();
        if (tid == 0) carry += buf[1023];
        __syncthreads();
    }
    if (threadIdx.x == 0) row_ptr[n] = carry;
}

__global__ void fill_kernel(const int* __restrict__ src, const int* __restrict__ dst,
                            const int* __restrict__ row_ptr, int* __restrict__ cursor,
                            int* __restrict__ csr_src, int E) {
    int e = blockIdx.x * blockDim.x + threadIdx.x;
    if (e < E) {
        int d = dst[e];
        int p = atomicAdd(&cursor[d], 1);
        csr_src[row_ptr[d] + p] = src[e];
    }
}

// ---------------- x0 copy with row padding ----------------
__global__ void copy_pad(const float* __restrict__ src, float* __restrict__ dst) {
    size_t i = (size_t)blockIdx.x * 256 + threadIdx.x;   // float4 index
    size_t row = i >> 6;                                 // 64 float4 per row
    float4 v = make_float4(0.f, 0.f, 0.f, 0.f);
    if (row < NN) v = reinterpret_cast<const float4*>(src)[i];
    reinterpret_cast<float4*>(dst)[i] = v;
}

// ---------------- split-bf16 MFMA GEMM ----------------
// C = epilogue(A @ W^T + bias), A: fp32 [rows][256] (row-padded), W: fp32 [*][256]
// Dual-K (K=512): A = [A1 | A2] along k, B = [B1 | B2] (concat at k=256).
// fp32 operands split 3-way to bf16 in staging; 6-term MFMA product == fp32 precision.
template <int MODE>
__global__ __launch_bounds__(256, 2)
void gemm_split(const float* __restrict__ A1, const float* __restrict__ A2,
                const float* __restrict__ B1, const float* __restrict__ B2,
                const float* __restrict__ bias1, const float* __restrict__ bias2,
                const float* __restrict__ aux1, const float* __restrict__ aux2,
                float* __restrict__ out, int M, int K) {
    __shared__ u16 sA[3][BM][LDP];
    __shared__ u16 sB[3][BN][LDP];

    const int tid = threadIdx.x;
    const int lane = tid & 63;
    const int wv = tid >> 6;            // wave 0..3
    const int wr = wv >> 1;             // wave row 0..1 (64 rows each)
    const int wc = wv & 1;              // wave col 0..1 (32 cols each)
    const int frow = lane & 15;
    const int kg = lane >> 4;           // 0..3

    const int rowBase = blockIdx.x * BM;
    const int colBase = blockIdx.y * BN;

    // staging maps
    const int srowA = tid >> 1;         // 0..127
    const int scolA = (tid & 1) * 16;
    const int srowB = tid >> 2;         // 0..63
    const int scolB = (tid & 3) * 8;

    f32x4 acc[4][2] = {};

    for (int k0 = 0; k0 < K; k0 += BK) {
        const float* Ap; const float* Bp; int kc;
        if (k0 < DD) { Ap = A1; Bp = B1; kc = k0; }
        else         { Ap = A2; Bp = B2; kc = k0 - DD; }

        // global loads (issue before barrier to hide latency)
        const float* ga = Ap + (size_t)(rowBase + srowA) * DD + kc + scolA;
        const float* gb = Bp + (size_t)(colBase + srowB) * DD + kc + scolB;
        float4 va[4], vb[2];
#pragma unroll
        for (int g = 0; g < 4; ++g) va[g] = *reinterpret_cast<const float4*>(ga + 4 * g);
#pragma unroll
        for (int g = 0; g < 2; ++g) vb[g] = *reinterpret_cast<const float4*>(gb + 4 * g);

        __syncthreads();   // previous iteration's LDS reads complete

        // split & write A
#pragma unroll
        for (int g = 0; g < 4; ++g) {
            u16 h0,m0,l0,h1,m1,l1,h2,m2,l2,h3,m3,l3;
            split3(va[g].x, h0,m0,l0); split3(va[g].y, h1,m1,l1);
            split3(va[g].z, h2,m2,l2); split3(va[g].w, h3,m3,l3);
            uint2 uh = make_uint2(pk(h0,h1), pk(h2,h3));
            uint2 um = make_uint2(pk(m0,m1), pk(m2,m3));
            uint2 ul = make_uint2(pk(l0,l1), pk(l2,l3));
            *reinterpret_cast<uint2*>(&sA[0][srowA][scolA + 4 * g]) = uh;
            *reinterpret_cast<uint2*>(&sA[1][srowA][scolA + 4 * g]) = um;
            *reinterpret_cast<uint2*>(&sA[2][srowA][scolA + 4 * g]) = ul;
        }
        // split & write B
#pragma unroll
        for (int g = 0; g < 2; ++g) {
            u16 h0,m0,l0,h1,m1,l1,h2,m2,l2,h3,m3,l3;
            split3(vb[g].x, h0,m0,l0); split3(vb[g].y, h1,m1,l1);
            split3(vb[g].z, h2,m2,l2); split3(vb[g].w, h3,m3,l3);
            uint2 uh = make_uint2(pk(h0,h1), pk(h2,h3));
            uint2 um = make_uint2(pk(m0,m1), pk(m2,m3));
            uint2 ul = make_uint2(pk(l0,l1), pk(l2,l3));
            *reinterpret_cast<uint2*>(&sB[0][srowB][scolB + 4 * g]) = uh;
            *reinterpret_cast<uint2*>(&sB[1][srowB][scolB + 4 * g]) = um;
            *reinterpret_cast<uint2*>(&sB[2][srowB][scolB + 4 * g]) = ul;
        }
        __syncthreads();

        // A fragments (hi/mid/lo x 4 m-frags)
        bf16x8 afr[3][4];
#pragma unroll
        for (int mf = 0; mf < 4; ++mf) {
            int ar = wr * 64 + mf * 16 + frow;
            afr[0][mf] = *reinterpret_cast<const bf16x8*>(&sA[0][ar][kg * 8]);
            afr[1][mf] = *reinterpret_cast<const bf16x8*>(&sA[1][ar][kg * 8]);
            afr[2][mf] = *reinterpret_cast<const bf16x8*>(&sA[2][ar][kg * 8]);
        }
#pragma unroll
        for (int nf = 0; nf < 2; ++nf) {
            int br = wc * 32 + nf * 16 + frow;
            bf16x8 bh = *reinterpret_cast<const bf16x8*>(&sB[0][br][kg * 8]);
            bf16x8 bm = *reinterpret_cast<const bf16x8*>(&sB[1][br][kg * 8]);
            bf16x8 bl = *reinterpret_cast<const bf16x8*>(&sB[2][br][kg * 8]);
#pragma unroll
            for (int mf = 0; mf < 4; ++mf) {
                f32x4 c = acc[mf][nf];
                c = __builtin_amdgcn_mfma_f32_16x16x32_bf16(afr[0][mf], bh, c, 0, 0, 0);
                c = __builtin_amdgcn_mfma_f32_16x16x32_bf16(afr[0][mf], bm, c, 0, 0, 0);
                c = __builtin_amdgcn_mfma_f32_16x16x32_bf16(afr[1][mf], bh, c, 0, 0, 0);
                c = __builtin_amdgcn_mfma_f32_16x16x32_bf16(afr[0][mf], bl, c, 0, 0, 0);
                c = __builtin_amdgcn_mfma_f32_16x16x32_bf16(afr[2][mf], bh, c, 0, 0, 0);
                c = __builtin_amdgcn_mfma_f32_16x16x32_bf16(afr[1][mf], bm, c, 0, 0, 0);
                acc[mf][nf] = c;
            }
        }
    }

    // epilogue
#pragma unroll
    for (int nf = 0; nf < 2; ++nf) {
        int gc = colBase + wc * 32 + nf * 16 + frow;
        float b1v = bias1[gc];
        float b2v = 0.0f;
        if (MODE == M_RGATE || MODE == M_ZGATE) b2v = bias2[gc];
#pragma unroll
        for (int mf = 0; mf < 4; ++mf) {
            f32x4 a = acc[mf][nf];
#pragma unroll
            for (int j = 0; j < 4; ++j) {
                int gr = rowBase + wr * 64 + mf * 16 + kg * 4 + j;
                if (gr < M) {
                    float v = a[j] + b1v + b2v;
                    size_t off = (size_t)gr * DD + gc;
                    if (MODE == M_PLAIN) {
                        out[off] = v;
                    } else if (MODE == M_RELU) {
                        out[off] = fmaxf(v, 0.0f);
                    } else if (MODE == M_RGATE) {
                        float r = sigmoidf_(v);
                        out[off] = tanhf(aux1[off] + r * aux2[off]);
                    } else { // M_ZGATE
                        float z = sigmoidf_(v);
                        out[off] = (1.0f - z) * aux1[off] + z * aux2[off];
                    }
                }
            }
        }
    }
}

// ---------------- segment sum (gather over CSR, fp32) ----------------
__global__ __launch_bounds__(256)
void segsum_kernel(const float* __restrict__ h, const int* __restrict__ row_ptr,
                   const int* __restrict__ csr_src, float* __restrict__ msg, int n) {
    int node = blockIdx.x * 4 + threadIdx.y;
    if (node >= n) return;
    int d4 = threadIdx.x * 4;
    int s = row_ptr[node];
    int e = row_ptr[node + 1];
    float4 acc = make_float4(0.f, 0.f, 0.f, 0.f);
    for (int j = s; j < e; ++j) {
        int sn = csr_src[j];
        float4 v = *reinterpret_cast<const float4*>(&h[(size_t)sn * DD + d4]);
        acc.x += v.x; acc.y += v.y; acc.z += v.z; acc.w += v.w;
    }
    *reinterpret_cast<float4*>(&msg[(size_t)node * DD + d4]) = acc;
}

// ---------------- launch ----------------

extern "C" void kernel_launch(void* const* d_in, const int* in_sizes, int n_in,
                              void* d_out, int out_size, void* d_ws, size_t ws_size,
                              hipStream_t stream) {
    const float* x0  = (const float*)d_in[0];
    const float* W1  = (const float*)d_in[1];
    const float* b1  = (const float*)d_in[2];
    const float* W2  = (const float*)d_in[3];
    const float* b2  = (const float*)d_in[4];
    const float* Wih = (const float*)d_in[5];
    const float* bih = (const float*)d_in[6];
    const float* Whh = (const float*)d_in[7];
    const float* bhh = (const float*)d_in[8];
    const int*   src = (const int*)d_in[9];
    const int*   dst = (const int*)d_in[10];

    // workspace: 4 padded activation buffers + CSR ints  (~208.8 MB, same as R1)
    char* ws = (char*)d_ws;
    const size_t NB = (size_t)NNP * DD * sizeof(float);   // 51.25 MB
    float* xf  = (float*)(ws);
    float* hb  = (float*)(ws + NB);
    float* t1  = (float*)(ws + 2 * NB);
    float* msg = (float*)(ws + 3 * NB);
    int* counts  = (int*)(ws + 4 * NB);
    int* cursor  = counts + NN;
    int* row_ptr = cursor + NN;            // NN+1 ints
    int* csr     = row_ptr + NN + 8;       // NE ints

    // CSR build
    zero_kernel<<<(2 * NN + 255) / 256, 256, 0, stream>>>(counts, 2 * NN);
    hist_kernel<<<(NE + 255) / 256, 256, 0, stream>>>(dst, counts, NE);
    scan_kernel<<<1, 1024, 0, stream>>>(counts, row_ptr, NN);
    fill_kernel<<<(NE + 255) / 256, 256, 0, stream>>>(src, dst, row_ptr, cursor, csr, NE);

    // x0 -> xf (pad rows zeroed)
    copy_pad<<<(NNP * 64 + 255) / 256, 256, 0, stream>>>(x0, xf);

    const dim3 grid(NNP / BM, DD / BN);   // 391 x 4

    for (int s = 0; s < NSTEPS; ++s) {
        float* xc = (s & 1) ? hb : xf;    // current x (padded)
        float* hc = (s & 1) ? xf : hb;    // scratch; becomes next x
        float* outp = (s == NSTEPS - 1) ? (float*)d_out : hc;

        // t1 = ReLU(x @ W1^T + b1)
        gemm_split<M_RELU><<<grid, 256, 0, stream>>>(
            xc, xc, W1, W1, b1, nullptr, nullptr, nullptr, t1, NN, 256);
        // h = t1 @ W2^T + b2  -> hc
        gemm_split<M_PLAIN><<<grid, 256, 0, stream>>>(
            t1, t1, W2, W2, b2, nullptr, nullptr, nullptr, hc, NN, 256);
        // msg = segment_sum(h[src], dst)
        segsum_kernel<<<dim3((NN + 3) / 4), dim3(64, 4), 0, stream>>>(hc, row_ptr, csr, msg, NN);
        // Gxn = msg @ Wih_n^T + bih_n  -> t1 (t1 dead)
        gemm_split<M_PLAIN><<<grid, 256, 0, stream>>>(
            msg, msg, Wih + 512 * 256, Wih + 512 * 256, bih + 512, nullptr,
            nullptr, nullptr, t1, NN, 256);
        // Ghn = x @ Whh_n^T + bhh_n  -> hc (h dead)
        gemm_split<M_PLAIN><<<grid, 256, 0, stream>>>(
            xc, xc, Whh + 512 * 256, Whh + 512 * 256, bhh + 512, nullptr,
            nullptr, nullptr, hc, NN, 256);
        // T = tanh(Gxn + r * Ghn), r = sigmoid([msg|x] @ [Wih_r|Whh_r]^T + bih_r + bhh_r)
        //   -> t1 in place (each element read+written by its own thread only)
        gemm_split<M_RGATE><<<grid, 256, 0, stream>>>(
            msg, xc, Wih, Whh, bih, bhh, t1, hc, t1, NN, 512);
        // out = (1-z)*T + z*x, z = sigmoid([msg|x] @ [Wih_z|Whh_z]^T + ...)  -> hc (or d_out)
        gemm_split<M_ZGATE><<<grid, 256, 0, stream>>>(
            msg, xc, Wih + 256 * 256, Whh + 256 * 256, bih + 256, bhh + 256,
            t1, xc, outp, NN, 512);
    }
}